// Round 4
// baseline (1388.563 us; speedup 1.0000x reference)
//
#include <hip/hip_runtime.h>
#include <hip/hip_bf16.h>
#include <cstdint>

typedef __attribute__((ext_vector_type(8))) short short8;
typedef __attribute__((ext_vector_type(4))) short short4v;
typedef __attribute__((ext_vector_type(4))) float float4v;

#define LOG2E 1.44269504088896340736f
#define LN2   0.69314718055994530942f

#if __has_builtin(__builtin_amdgcn_exp2f)
__device__ __forceinline__ float fexp2(float x){ return __builtin_amdgcn_exp2f(x); }
#else
__device__ __forceinline__ float fexp2(float x){ return exp2f(x); }
#endif
#if __has_builtin(__builtin_amdgcn_logf)
__device__ __forceinline__ float flog2(float x){ return __builtin_amdgcn_logf(x); }
#else
__device__ __forceinline__ float flog2(float x){ return log2f(x); }
#endif

// hhat = log2(1 + 2^zhat); biases pre-scaled by log2e so GEMM on hhat yields
// the next zhat directly (ln2 * log2e == 1 cancels).
__device__ __forceinline__ float softplus_hat(float zh){
  return flog2(1.0f + fexp2(zh));
}

// softplus output > 0 -> truncation (RTZ) to bf16 is a 1-instr shift.
__device__ __forceinline__ unsigned short bf16_trunc(float f){
  return (unsigned short)(__builtin_bit_cast(unsigned int, f) >> 16);
}

// fp16 handoff for z (MFMA waves -> VALU waves). RNE cast: |err| <= 2^-12
// relative on z -> h error ~8x below the bf16 truncation already applied to h.
__device__ __forceinline__ unsigned short f16_rne(float f){
  _Float16 h = (_Float16)f;
  return __builtin_bit_cast(unsigned short, h);
}
__device__ __forceinline__ float f16_to_f32(unsigned short u){
  _Float16 h = __builtin_bit_cast(_Float16, u);
  return (float)h;
}

// h tile layout (per 64-row tile): addr(m,c) = m*264 + (m>>2)*16 + c elems.
// (champion layout: 528 B row stride keeps ds_read_b128 aligned; +16-elem
// skew per 4 rows keeps A-reads and b16 column-writes at the wave64
// 2-lanes/bank minimum.)
#define HSTRIDE 264
#define MISTEP  4288                    // 16*264 + 4*16
#define HSIZE   (64 * 264 + 16 * 16)    // 17152 elems = 34304 B per tile

// z handoff buffer: column-major fp16, zb[c][m], stride 68 elems = 136 B
// (multiple of 8 B -> aligned b64; 16B-misalign avoided by using b64 ops).
#define ZSTRIDE 68
#define ZSIZE   (256 * ZSTRIDE)         // 17408 elems = 34816 B per buffer

// ---------------------------------------------------------------------------
// Pre-pass: Wh [S,4,256,256] fp32 -> bf16 slabs Wt[s*4+l][kb][n][ki]
// (kb = k/32, ki = k%32). B-frags read from GLOBAL: lanes {n,n+16,n+32,n+48}
// cover row n's 64B contiguously -> 1KB/wave-instr from L2.
// ---------------------------------------------------------------------------
__global__ void convert_wh(const float* __restrict__ Wh,
                           unsigned short* __restrict__ Wt){
  int e = blockIdx.x * 256 + threadIdx.x;          // 0 .. 2^21-1
  int n  = e & 255;
  int k  = (e >> 8) & 255;
  int sl = e >> 16;
  float v = Wh[e];
  __hip_bfloat16 h = __float2bfloat16(v);
  Wt[(sl << 16) + ((k >> 5) << 13) + (n << 5) + (k & 31)] =
      __builtin_bit_cast(unsigned short, h);
}

__device__ __forceinline__ float4v bf16_mfma(short8 a, short8 b, float4v c){
  return __builtin_amdgcn_mfma_f32_16x16x32_bf16(a, b, c, 0, 0, 0);
}

// layer-0 (K=3) for rows 4j..4j+3 of one 64-row tile, column c
__device__ __forceinline__ void l0_rows(
    unsigned short* __restrict__ ht, const float4v* __restrict__ c4,
    int j, int c, float w0, float w1, float w2, float bb)
{
  float4v x0 = c4[j*3+0], x1 = c4[j*3+1], x2 = c4[j*3+2];
  float z0 = fmaf(x0.z, w2, fmaf(x0.y, w1, fmaf(x0.x, w0, bb)));
  float z1 = fmaf(x1.y, w2, fmaf(x1.x, w1, fmaf(x0.w, w0, bb)));
  float z2 = fmaf(x2.x, w2, fmaf(x1.w, w1, fmaf(x1.z, w0, bb)));
  float z3 = fmaf(x2.w, w2, fmaf(x2.z, w1, fmaf(x2.y, w0, bb)));
  ht[(4*j+0)*HSTRIDE + j*16 + c] = bf16_trunc(softplus_hat(z0));
  ht[(4*j+1)*HSTRIDE + j*16 + c] = bf16_trunc(softplus_hat(z1));
  ht[(4*j+2)*HSTRIDE + j*16 + c] = bf16_trunc(softplus_hat(z2));
  ht[(4*j+3)*HSTRIDE + j*16 + c] = bf16_trunc(softplus_hat(z3));
}

// ---------------------------------------------------------------------------
// K-loop (champion schedule, untouched): 16 mfma/kb, A prefetch depth 1 from
// LDS, rotating depth-3 B prefetch from global, slot=(8*PH+kb)%3 continuous
// across all 8 phases; kb 5..7 prefetch the NEXT phase's kb 0..2 from bn.
// ---------------------------------------------------------------------------
template<int PH, bool LOADN>
__device__ __forceinline__ void mfma_phase(
    const unsigned short* __restrict__ bb,
    const unsigned short* __restrict__ bn,
    const unsigned short* __restrict__ aptr,
    short8 (&bq)[3][4], float4v (&acc)[4][4])
{
  short8 a0[4], a1[4];
  #pragma unroll
  for (int mi = 0; mi < 4; ++mi)
    a0[mi] = *(const short8*)(aptr + mi * MISTEP);

  #pragma unroll
  for (int kb = 0; kb < 8; ++kb) {
    short8* cur = (kb & 1) ? a1 : a0;
    short8* nxt = (kb & 1) ? a0 : a1;
    if (kb < 7) {                                  // A prefetch depth 1 (LDS)
      #pragma unroll
      for (int mi = 0; mi < 4; ++mi)
        nxt[mi] = *(const short8*)(aptr + (kb + 1) * 32 + mi * MISTEP);
    }
    const int slot = (8 * PH + kb) % 3;            // compile-time (unrolled)
    #pragma unroll
    for (int mi = 0; mi < 4; ++mi)
      #pragma unroll
      for (int ni = 0; ni < 4; ++ni)
        acc[mi][ni] = bf16_mfma(cur[mi], bq[slot][ni], acc[mi][ni]);
    if (kb < 5) {                                  // B depth-3, this phase
      #pragma unroll
      for (int ni = 0; ni < 4; ++ni)
        bq[slot][ni] = *(const short8*)(bb + (kb + 3) * 8192 + ni * 512);
    } else if (LOADN) {                            // next phase's kb 0..2
      #pragma unroll
      for (int ni = 0; ni < 4; ++ni)
        bq[slot][ni] = *(const short8*)(bn + (kb - 5) * 8192 + ni * 512);
    }
  }
}

// ---------------------------------------------------------------------------
// WAVE-SPECIALIZED fused MLP (m114 configuration: per SIMD, one pure-MFMA
// wave + one pure-VALU wave -> matrix and VALU pipes run concurrently).
// 512-thread block, 1 block/CU: waves 0-3 do MFMA only (z -> fp16 LDS);
// waves 4-7 do softplus only (z -> bf16 h tile). Two 64-row tiles alternate:
//   P0: MFMA zA<-hA(0)        | VALU idle
//   P1: MFMA zB<-hB(0)        | VALU hA(1)<-sp(zA)
//   ...                       |
//   P7: MFMA zB<-hB(3)        | VALU hA(4)<-sp(zA)
//   P8: idle                  | VALU hB(4)<-sp(zB)
// B-slab traffic per output row unchanged vs champion (2 phases/layer,
// 128 rows). LDS 140.8 KB: 2 h tiles + 2 z buffers + staging.
// ---------------------------------------------------------------------------
__global__ __launch_bounds__(512, 2) void series_mlp(
    const float* __restrict__ coords,
    const float* __restrict__ W0, const float* __restrict__ b0,
    const float* __restrict__ bh,
    const float* __restrict__ Wout, const float* __restrict__ bout,
    const unsigned short* __restrict__ Wt,
    float* __restrict__ out)
{
  __shared__ __align__(16) unsigned short h_lds[2 * HSIZE];   // 68608 B
  __shared__ __align__(16) unsigned short zbuf[2][ZSIZE];     // 69632 B
  __shared__ float cbuf[384];
  __shared__ float wout_s[256];

  const int tid  = threadIdx.x;
  const int lane = tid & 63;
  const int wave = tid >> 6;
  const int s    = blockIdx.x & 7;           // series == XCD
  const int m0   = (blockIdx.x >> 3) * 128;  // 1563 m-blocks; tail tile B dead

  const int q    = lane >> 4;
  const int lr   = lane & 15;
  const int colb = ((wave & 3) << 6) + lr;   // MFMA waves: col strip base
  const int cc   = tid & 255;                // VALU waves: owned column

  // stage coords (128 rows; tail clamps -> finite garbage, never written out)
  if (tid < 384) {
    int idx = m0 * 3 + tid;
    cbuf[tid] = coords[idx < 599999 ? idx : 599999];
  }
  if (tid < 256) wout_s[tid] = Wout[(s << 8) + tid];

  // B-frag lane base + initial 3-slot fill (MFMA waves only; issued early so
  // L2 latency hides under layer 0)
  const unsigned short* bbase0 = Wt + ((s << 2) << 16) + (colb << 5) + (q << 3);
  short8 bq[3][4];
  if (wave < 4) {
    #pragma unroll
    for (int i = 0; i < 3; ++i)
      #pragma unroll
      for (int ni = 0; ni < 4; ++ni)
        bq[i][ni] = *(const short8*)(bbase0 + i * 8192 + ni * 512);
  }

  // A-frag lane bases per tile (champion addressing, verbatim)
  const unsigned short* aptrA = h_lds + lr * HSTRIDE + (lr >> 2) * 16 + (q << 3);
  const unsigned short* aptrB = aptrA + HSIZE;

  const float* bh_s = bh + (s << 10);
  const float4v* c4 = (const float4v*)cbuf;

  __syncthreads();                      // staging ready

  // ---------------- layer 0: all 8 waves, thread (cc, th) does 64 rows ----
  {
    const int th = tid >> 8;            // 0 = tile A, 1 = tile B
    unsigned short* ht = h_lds + th * HSIZE;
    const float4v* cp = c4 + th * 48;
    const float w0  = W0[(s * 3 + 0) * 256 + cc] * LOG2E;
    const float w1  = W0[(s * 3 + 1) * 256 + cc] * LOG2E;
    const float w2  = W0[(s * 3 + 2) * 256 + cc] * LOG2E;
    const float bb0 = b0[s * 256 + cc] * LOG2E;
    #pragma unroll
    for (int j = 0; j < 16; ++j)
      l0_rows(ht, cp, j, cc, w0, w1, w2, bb0);
  }
  __syncthreads();                      // hA(0), hB(0) ready

  float4v acc[4][4];

#define INIT_ACC(LIDX)                                                        \
  {                                                                           \
    float bias[4];                                                            \
    _Pragma("unroll")                                                         \
    for (int ni = 0; ni < 4; ++ni)                                            \
      bias[ni] = bh_s[(LIDX) * 256 + colb + ni * 16] * LOG2E;                 \
    _Pragma("unroll")                                                         \
    for (int mi = 0; mi < 4; ++mi)                                            \
      _Pragma("unroll")                                                       \
      for (int ni = 0; ni < 4; ++ni)                                          \
        acc[mi][ni] = (float4v){bias[ni], bias[ni], bias[ni], bias[ni]};      \
  }

  // MFMA phase: K-loop + packed fp16 z write (frag = 4 consecutive rows at
  // fixed col -> one aligned ds_write_b64 into column-major zbuf).
#define MFMA_PHASE(PH, BB, BN, LOADN, APTR)                                   \
  if (wave < 4) {                                                             \
    INIT_ACC((PH) >> 1)                                                       \
    mfma_phase<PH, LOADN>(BB, BN, APTR, bq, acc);                             \
    unsigned short* zp = &zbuf[(PH) & 1][colb * ZSTRIDE + (q << 2)];          \
    _Pragma("unroll")                                                         \
    for (int mi = 0; mi < 4; ++mi)                                            \
      _Pragma("unroll")                                                       \
      for (int ni = 0; ni < 4; ++ni) {                                        \
        float4v v = acc[mi][ni];                                              \
        short4v pk = {(short)f16_rne(v.x), (short)f16_rne(v.y),               \
                      (short)f16_rne(v.z), (short)f16_rne(v.w)};              \
        *(short4v*)(zp + ni * (16 * ZSTRIDE) + mi * 16) = pk;                 \
      }                                                                       \
  }

  // VALU phase: column cc, 64 rows: fp16 z -> softplus -> bf16 h (skewed).
#define SP_PHASE(ZI, HT)                                                      \
  if (wave >= 4) {                                                            \
    const unsigned short* zp = &zbuf[ZI][cc * ZSTRIDE];                       \
    unsigned short* ht = (HT);                                                \
    _Pragma("unroll")                                                         \
    for (int j = 0; j < 16; ++j) {                                            \
      short4v zv = *(const short4v*)(zp + j * 4);                             \
      _Pragma("unroll")                                                       \
      for (int i = 0; i < 4; ++i) {                                           \
        const int m = j * 4 + i;                                              \
        float f = f16_to_f32((unsigned short)zv[i]);                          \
        ht[m * HSTRIDE + (m >> 2) * 16 + cc] = bf16_trunc(softplus_hat(f));   \
      }                                                                       \
    }                                                                         \
  }

  const unsigned short* B0 = bbase0;
  const unsigned short* B1 = bbase0 + 65536;
  const unsigned short* B2 = bbase0 + 2 * 65536;
  const unsigned short* B3 = bbase0 + 3 * 65536;

  MFMA_PHASE(0, B0, B0, true,  aptrA)
  __syncthreads();
  MFMA_PHASE(1, B0, B1, true,  aptrB)  SP_PHASE(0, h_lds)
  __syncthreads();
  MFMA_PHASE(2, B1, B1, true,  aptrA)  SP_PHASE(1, h_lds + HSIZE)
  __syncthreads();
  MFMA_PHASE(3, B1, B2, true,  aptrB)  SP_PHASE(0, h_lds)
  __syncthreads();
  MFMA_PHASE(4, B2, B2, true,  aptrA)  SP_PHASE(1, h_lds + HSIZE)
  __syncthreads();
  MFMA_PHASE(5, B2, B3, true,  aptrB)  SP_PHASE(0, h_lds)
  __syncthreads();
  MFMA_PHASE(6, B3, B3, true,  aptrA)  SP_PHASE(1, h_lds + HSIZE)
  __syncthreads();
  MFMA_PHASE(7, B3, B3, false, aptrB)  SP_PHASE(0, h_lds)
  __syncthreads();
  SP_PHASE(1, h_lds + HSIZE)           // P8: hB(4) (MFMA waves idle)
  __syncthreads();

#undef MFMA_PHASE
#undef SP_PHASE
#undef INIT_ACC

  // ---------------- epilogue: out[m] = LN2 * sum_c h4[m][c]*Wout[c] + bout --
  {
    const int rt = tid >> 2;            // 0..127 (row within block)
    const int qq = tid & 3;             // 64-col quarter
    const int lm = rt & 63;
    const unsigned short* hrow = h_lds + (rt >> 6) * HSIZE
        + lm * HSTRIDE + (lm >> 2) * 16 + qq * 64;
    float sum = 0.f;
    #pragma unroll
    for (int j = 0; j < 8; ++j) {
      short8 hv = *(const short8*)(hrow + j * 8);
      #pragma unroll
      for (int i = 0; i < 8; ++i) {
        float f = __builtin_bit_cast(float,
                    (unsigned int)((unsigned short)hv[i]) << 16);
        sum = fmaf(f, wout_s[qq * 64 + j * 8 + i], sum);
      }
    }
    float* red = (float*)zbuf;          // zbuf free after P8 barrier
    red[tid] = sum;
    __syncthreads();
    if (tid < 128) {
      int row = m0 + tid;
      if (row < 200000) {
        float4v r4 = ((const float4v*)red)[tid];
        out[row * 8 + s] =
            fmaf(LN2, (r4.x + r4.y) + (r4.z + r4.w), bout[s]);
      }
    }
  }
}

// ---------------------------------------------------------------------------
// Fallback (scratch-free), fp32 VALU — only if ws_size < 4 MiB.
// ---------------------------------------------------------------------------
__global__ __launch_bounds__(256) void series_mlp_slow(
    const float* __restrict__ coords,
    const float* __restrict__ W0, const float* __restrict__ b0,
    const float* __restrict__ Wh, const float* __restrict__ bh,
    const float* __restrict__ Wout, const float* __restrict__ bout,
    float* __restrict__ out)
{
  __shared__ float hh[64 * 256];
  __shared__ float cbuf[192];
  __shared__ float red[256];
  const int tid = threadIdx.x;
  const int s   = blockIdx.y;
  const int m0  = blockIdx.x * 64;

  if (tid < 192) cbuf[tid] = coords[m0 * 3 + tid];
  __syncthreads();
  {
    const float w0 = W0[(s * 3 + 0) * 256 + tid];
    const float w1 = W0[(s * 3 + 1) * 256 + tid];
    const float w2 = W0[(s * 3 + 2) * 256 + tid];
    const float bb = b0[s * 256 + tid];
    for (int m = 0; m < 64; ++m) {
      float z = fmaf(cbuf[m * 3 + 2], w2,
                fmaf(cbuf[m * 3 + 1], w1,
                fmaf(cbuf[m * 3 + 0], w0, bb)));
      hh[m * 256 + tid] = LN2 * softplus_hat(z * LOG2E);
    }
  }
  __syncthreads();

  for (int l = 0; l < 4; ++l) {
    const float* W = Wh + (((s << 2) + l) << 16);
    const float bb = bh[((s << 2) + l) * 256 + tid];
    float acc[64];
    #pragma unroll
    for (int m = 0; m < 64; ++m) acc[m] = bb;
    for (int kc = 0; kc < 64; ++kc) {
      float w0 = W[(kc * 4 + 0) * 256 + tid];
      float w1 = W[(kc * 4 + 1) * 256 + tid];
      float w2 = W[(kc * 4 + 2) * 256 + tid];
      float w3 = W[(kc * 4 + 3) * 256 + tid];
      #pragma unroll
      for (int m = 0; m < 64; ++m) {
        float4v hv = *(const float4v*)&hh[m * 256 + kc * 4];
        acc[m] = fmaf(hv.w, w3, fmaf(hv.z, w2,
                 fmaf(hv.y, w1, fmaf(hv.x, w0, acc[m]))));
      }
    }
    __syncthreads();
    #pragma unroll
    for (int m = 0; m < 64; ++m)
      hh[m * 256 + tid] = LN2 * softplus_hat(acc[m] * LOG2E);
    __syncthreads();
  }
  {
    const int m = tid >> 2, qq = tid & 3;
    const float* wv = Wout + (s << 8);
    float sum = 0.f;
    for (int i = 0; i < 16; ++i) {
      int kk = (qq << 6) + ((((tid & 15) + i) << 2) & 63);
      float4v hv = *(const float4v*)&hh[m * 256 + kk];
      sum += hv.x * wv[kk] + hv.y * wv[kk + 1] + hv.z * wv[kk + 2] + hv.w * wv[kk + 3];
    }
    red[tid] = sum;
    __syncthreads();
    if (tid < 64)
      out[(m0 + tid) * 8 + s] =
          red[tid * 4] + red[tid * 4 + 1] + red[tid * 4 + 2] + red[tid * 4 + 3] + bout[s];
  }
}

extern "C" void kernel_launch(void* const* d_in, const int* in_sizes, int n_in,
                              void* d_out, int out_size, void* d_ws, size_t ws_size,
                              hipStream_t stream) {
  const float* coords = (const float*)d_in[0];
  const float* W0     = (const float*)d_in[1];
  const float* b0     = (const float*)d_in[2];
  const float* Wh     = (const float*)d_in[3];
  const float* bh     = (const float*)d_in[4];
  const float* Wout   = (const float*)d_in[5];
  const float* bout   = (const float*)d_in[6];
  float* out = (float*)d_out;

  const size_t WT_BYTES = (size_t)8 * 4 * 256 * 256 * 2;   // 4 MiB bf16 slabs
  if (ws_size >= WT_BYTES) {
    unsigned short* Wt = (unsigned short*)d_ws;
    convert_wh<<<8192, 256, 0, stream>>>(Wh, Wt);
    // 1563 m-blocks x 128 rows x 8 series (1562*128+64 = 200000, tail B dead)
    series_mlp<<<dim3(12504), dim3(512), 0, stream>>>(
        coords, W0, b0, bh, Wout, bout, Wt, out);
  } else {
    series_mlp_slow<<<dim3(3125, 8), dim3(256), 0, stream>>>(
        coords, W0, b0, Wh, bh, Wout, bout, out);
  }
  // second tuple output: echo coords
  hipMemcpyAsync(out + (size_t)200000 * 8, coords,
                 (size_t)200000 * 3 * sizeof(float),
                 hipMemcpyDeviceToDevice, stream);
}

// Round 5
// 897.529 us; speedup vs baseline: 1.5471x; 1.5471x over previous
//
#include <hip/hip_runtime.h>
#include <hip/hip_bf16.h>
#include <cstdint>

typedef __attribute__((ext_vector_type(8))) short short8;
typedef __attribute__((ext_vector_type(4))) float float4v;

#define LOG2E 1.44269504088896340736f
#define LN2   0.69314718055994530942f

#if __has_builtin(__builtin_amdgcn_exp2f)
__device__ __forceinline__ float fexp2(float x){ return __builtin_amdgcn_exp2f(x); }
#else
__device__ __forceinline__ float fexp2(float x){ return exp2f(x); }
#endif
#if __has_builtin(__builtin_amdgcn_logf)
__device__ __forceinline__ float flog2(float x){ return __builtin_amdgcn_logf(x); }
#else
__device__ __forceinline__ float flog2(float x){ return log2f(x); }
#endif

// hhat = log2(1 + 2^zhat); biases pre-scaled by log2e so GEMM on hhat yields
// the next zhat directly (ln2 * log2e == 1 cancels).
__device__ __forceinline__ float softplus_hat(float zh){
  return flog2(1.0f + fexp2(zh));
}

// softplus output > 0 -> truncation (RTZ) to bf16 is a 1-instr shift.
__device__ __forceinline__ unsigned short bf16_trunc(float f){
  return (unsigned short)(__builtin_bit_cast(unsigned int, f) >> 16);
}

// h tile layout (per 64-row tile): addr(m,c) = m*264 + (m>>2)*16 + c elems.
// (round-0 champion layout, unchanged: 528 B row stride keeps ds_read_b128
// aligned; +16-elem skew per 4 rows keeps A-reads and scalar b16 C-writes at
// the wave64 2-lanes/bank minimum.)
#define HSTRIDE 264
#define MISTEP  4288                    // 16*264 + 4*16
#define HSIZE   (64 * 264 + 16 * 16)    // 17152 elems = 34304 B per tile

// ---------------------------------------------------------------------------
// Pre-pass: Wh [S,4,256,256] fp32 -> bf16 slabs Wt[s*4+l][kb][n][ki]
// (kb = k/32, ki = k%32). B-frags read from GLOBAL: lanes {n,n+16,n+32,n+48}
// cover row n's 64B contiguously -> 1KB/wave-instr from L2.
// ---------------------------------------------------------------------------
__global__ void convert_wh(const float* __restrict__ Wh,
                           unsigned short* __restrict__ Wt){
  int e = blockIdx.x * 256 + threadIdx.x;          // 0 .. 2^21-1
  int n  = e & 255;
  int k  = (e >> 8) & 255;
  int sl = e >> 16;
  float v = Wh[e];
  __hip_bfloat16 h = __float2bfloat16(v);
  Wt[(sl << 16) + ((k >> 5) << 13) + (n << 5) + (k & 31)] =
      __builtin_bit_cast(unsigned short, h);
}

__device__ __forceinline__ float4v bf16_mfma(short8 a, short8 b, float4v c){
  return __builtin_amdgcn_mfma_f32_16x16x32_bf16(a, b, c, 0, 0, 0);
}

// layer-0 (K=3) for rows 4j..4j+3 of one 64-row tile, column c
__device__ __forceinline__ void l0_rows(
    unsigned short* __restrict__ ht, const float4v* __restrict__ c4,
    int j, int c, float w0, float w1, float w2, float bb)
{
  float4v x0 = c4[j*3+0], x1 = c4[j*3+1], x2 = c4[j*3+2];
  float z0 = fmaf(x0.z, w2, fmaf(x0.y, w1, fmaf(x0.x, w0, bb)));
  float z1 = fmaf(x1.y, w2, fmaf(x1.x, w1, fmaf(x0.w, w0, bb)));
  float z2 = fmaf(x2.x, w2, fmaf(x1.w, w1, fmaf(x1.z, w0, bb)));
  float z3 = fmaf(x2.w, w2, fmaf(x2.z, w1, fmaf(x2.y, w0, bb)));
  ht[(4*j+0)*HSTRIDE + j*16 + c] = bf16_trunc(softplus_hat(z0));
  ht[(4*j+1)*HSTRIDE + j*16 + c] = bf16_trunc(softplus_hat(z1));
  ht[(4*j+2)*HSTRIDE + j*16 + c] = bf16_trunc(softplus_hat(z2));
  ht[(4*j+3)*HSTRIDE + j*16 + c] = bf16_trunc(softplus_hat(z3));
}

// softplus + write-back of 2 ELEMENTS (substep granularity) of the OTHER
// tile's acc. Frag idx = 2*kb + (sub>>1), elements r0..r0+1, r0 = (sub&1)*2.
// kb,sub compile-time after unrolling -> pure base+immediate LDS stores.
__device__ __forceinline__ void sp2s(const float4v (&acc)[4][4],
    unsigned short* __restrict__ cptr, int kb, int sub)
{
  const int idx = kb * 2 + (sub >> 1);
  const int mi = idx >> 2, ni = idx & 3;
  const int r0 = (sub & 1) * 2;
  float4v v = acc[mi][ni];
  #pragma unroll
  for (int r = r0; r < r0 + 2; ++r)
    cptr[mi * MISTEP + r * HSTRIDE + ni * 16] = bf16_trunc(softplus_hat(v[r]));
}

// softplus + output-dot of 2 elements of the OTHER tile's acc (last layer)
__device__ __forceinline__ void spdot2s(const float4v (&acc)[4][4],
    const float (&wv)[4], float (&p)[16], int kb, int sub)
{
  const int idx = kb * 2 + (sub >> 1);
  const int mi = idx >> 2, ni = idx & 3;
  const int r0 = (sub & 1) * 2;
  float4v v = acc[mi][ni];
  #pragma unroll
  for (int r = r0; r < r0 + 2; ++r)
    p[mi * 4 + r] = fmaf(softplus_hat(v[r]), wv[ni], p[mi * 4 + r]);
}

// ---------------------------------------------------------------------------
// One phase = champion K-loop split into 4 SUBSTEPS per kb, with
// sched_barrier(0) pins: {4 MFMA + mem-issue slot} / {~2 softplus elems}
// alternation. Memory issue distance preserved (A-prefetch sub 1 -> used
// next kb; B depth-3 global prefetch sub 3 -> used 3 kbs later).
// ---------------------------------------------------------------------------
template<int PH, bool LOADN, class F>
__device__ __forceinline__ void mfma_phase(
    const unsigned short* __restrict__ bb,   // this phase's slab + lane offset
    const unsigned short* __restrict__ bn,   // next phase's slab + lane offset
    const unsigned short* __restrict__ aptr, // h tile + lane A-base
    short8 (&bq)[3][4], float4v (&acc)[4][4], F&& other)
{
  short8 a0[4], a1[4];
  #pragma unroll
  for (int mi = 0; mi < 4; ++mi)
    a0[mi] = *(const short8*)(aptr + mi * MISTEP);

  #pragma unroll
  for (int kb = 0; kb < 8; ++kb) {
    short8* cur = (kb & 1) ? a1 : a0;
    short8* nxt = (kb & 1) ? a0 : a1;
    const int slot = (8 * PH + kb) % 3;            // compile-time (unrolled)
    #pragma unroll
    for (int sub = 0; sub < 4; ++sub) {
      // ---- MFMA group: A-frag cur[sub] x 4 B-frags ----
      #pragma unroll
      for (int ni = 0; ni < 4; ++ni)
        acc[sub][ni] = bf16_mfma(cur[sub], bq[slot][ni], acc[sub][ni]);
      // ---- memory-issue slots ----
      if (sub == 1 && kb < 7) {                    // A prefetch depth 1 (LDS)
        #pragma unroll
        for (int mi = 0; mi < 4; ++mi)
          nxt[mi] = *(const short8*)(aptr + (kb + 1) * 32 + mi * MISTEP);
      }
      if (sub == 3) {
        if (kb < 5) {                              // B depth-3, this phase
          #pragma unroll
          for (int ni = 0; ni < 4; ++ni)
            bq[slot][ni] = *(const short8*)(bb + (kb + 3) * 8192 + ni * 512);
        } else if (LOADN) {                        // next phase's kb 0..2
          #pragma unroll
          for (int ni = 0; ni < 4; ++ni)
            bq[slot][ni] = *(const short8*)(bn + (kb - 5) * 8192 + ni * 512);
        }
      }
      __builtin_amdgcn_sched_barrier(0);
      other(kb, sub);                              // ~2 softplus elems (VALU)
      __builtin_amdgcn_sched_barrier(0);
    }
  }
}

// ---------------------------------------------------------------------------
// Fused MLP: one workgroup owns TWO 64-row tiles (128 rows) in anti-phase.
// Each phase: K-loop(tile X, layer l) with tile Y's softplus interleaved
// at substep granularity. 4 waves, wave tile 64m x 64n, one series/block,
// s = blk&7. LDS: 2 x 34304 B tiles + cbuf = 70 KB -> 2 blocks/CU.
// All bh biases and Wout hoisted to prologue registers (loads hide under
// layer-0); phases carry no VMEM scalar traffic besides the B slabs.
// ---------------------------------------------------------------------------
__global__ __launch_bounds__(256, 2) void series_mlp(
    const float* __restrict__ coords,
    const float* __restrict__ W0, const float* __restrict__ b0,
    const float* __restrict__ bh,
    const float* __restrict__ Wout, const float* __restrict__ bout,
    const unsigned short* __restrict__ Wt,
    float* __restrict__ out)
{
  __shared__ __align__(16) unsigned short h_lds[2 * HSIZE];   // 68608 B
  __shared__ float cbuf[384];

  const int tid  = threadIdx.x;
  const int lane = tid & 63;
  const int wave = tid >> 6;
  const int s    = blockIdx.x & 7;           // series == XCD
  const int m0   = (blockIdx.x >> 3) * 128;  // 1563 m-blocks; tail tile1 dead

  const int q    = lane >> 4;
  const int lr   = lane & 15;
  const int colb = (wave << 6) + lr;

  // coords for 128 rows (tail block: clamp index -> finite garbage, unwritten)
  {
    int i1 = m0 * 3 + tid;
    int i2 = i1 + 256;
    cbuf[tid] = coords[i1 < 599999 ? i1 : 599999];
    if (tid < 128) cbuf[tid + 256] = coords[i2 < 599999 ? i2 : 599999];
  }

  // layer-0 weights for this thread's column (shared by both tiles)
  const int c = tid;
  const float w0  = W0[(s * 3 + 0) * 256 + c] * LOG2E;
  const float w1  = W0[(s * 3 + 1) * 256 + c] * LOG2E;
  const float w2  = W0[(s * 3 + 2) * 256 + c] * LOG2E;
  const float bb0 = b0[s * 256 + c] * LOG2E;

  // B-frag lane base + initial 3-slot fill (issued early: hides L2 latency
  // under the layer-0 VALU work)
  const unsigned short* bbase0 = Wt + ((s << 2) << 16) + (colb << 5) + (q << 3);
  short8 bq[3][4];
  #pragma unroll
  for (int i = 0; i < 3; ++i)
    #pragma unroll
    for (int ni = 0; ni < 4; ++ni)
      bq[i][ni] = *(const short8*)(bbase0 + i * 8192 + ni * 512);

  // bias/Wout preload (hoisted out of the phase stream; L2-resident)
  const float* bh_s = bh + (s << 10);
  float bias_r[4][4];
  #pragma unroll
  for (int l = 0; l < 4; ++l)
    #pragma unroll
    for (int ni = 0; ni < 4; ++ni)
      bias_r[l][ni] = bh_s[l * 256 + colb + ni * 16] * LOG2E;
  float wv[4];
  #pragma unroll
  for (int ni = 0; ni < 4; ++ni)
    wv[ni] = Wout[(s << 8) + colb + ni * 16];

  // A-frag / C-write lane bases per tile (champion addressing, verbatim)
  const unsigned short* aptrA = h_lds + lr * HSTRIDE + (lr >> 2) * 16 + (q << 3);
  const unsigned short* aptrB = aptrA + HSIZE;
  unsigned short* cptrA = h_lds + q * 1072 + colb;
  unsigned short* cptrB = cptrA + HSIZE;

  const float4v* c4 = (const float4v*)cbuf;

  __syncthreads();                      // cbuf ready
  #pragma unroll
  for (int j = 0; j < 16; ++j)          // layer 0, tile A (exposed prologue)
    l0_rows(h_lds, c4, j, c, w0, w1, w2, bb0);
  __syncthreads();                      // hA(0) ready

  float4v accA[4][4], accB[4][4];

#define INIT_ACC(ACC, LIDX)                                                   \
  {                                                                           \
    _Pragma("unroll")                                                         \
    for (int mi = 0; mi < 4; ++mi)                                            \
      _Pragma("unroll")                                                       \
      for (int ni = 0; ni < 4; ++ni)                                          \
        ACC[mi][ni] = (float4v){bias_r[LIDX][ni], bias_r[LIDX][ni],           \
                                bias_r[LIDX][ni], bias_r[LIDX][ni]};          \
  }

  const unsigned short* B0 = bbase0;
  const unsigned short* B1 = bbase0 + 65536;
  const unsigned short* B2 = bbase0 + 2 * 65536;
  const unsigned short* B3 = bbase0 + 3 * 65536;

  // P0: K(tA, l0) || layer-0 for tile B (one row-quad on subs 0 and 2)
  INIT_ACC(accA, 0)
  mfma_phase<0, true>(B0, B0, aptrA, bq, accA, [&](int kb, int sub){
    if (sub == 0) l0_rows(h_lds + HSIZE, c4 + 48, 2 * kb + 0, c, w0, w1, w2, bb0);
    if (sub == 2) l0_rows(h_lds + HSIZE, c4 + 48, 2 * kb + 1, c, w0, w1, w2, bb0);
  });
  __syncthreads();                      // hB(0) ready

  // P1: K(tB, l0) || softplus(accA) -> hA(1)
  INIT_ACC(accB, 0)
  mfma_phase<1, true>(B0, B1, aptrB, bq, accB,
      [&](int kb, int sub){ sp2s(accA, cptrA, kb, sub); });
  __syncthreads();                      // hA(1) ready

  // P2: K(tA, l1) || softplus(accB) -> hB(1)
  INIT_ACC(accA, 1)
  mfma_phase<2, true>(B1, B1, aptrA, bq, accA,
      [&](int kb, int sub){ sp2s(accB, cptrB, kb, sub); });
  __syncthreads();                      // hB(1) ready

  // P3: K(tB, l1) || softplus(accA) -> hA(2)
  INIT_ACC(accB, 1)
  mfma_phase<3, true>(B1, B2, aptrB, bq, accB,
      [&](int kb, int sub){ sp2s(accA, cptrA, kb, sub); });
  __syncthreads();                      // hA(2) ready

  // P4: K(tA, l2) || softplus(accB) -> hB(2)
  INIT_ACC(accA, 2)
  mfma_phase<4, true>(B2, B2, aptrA, bq, accA,
      [&](int kb, int sub){ sp2s(accB, cptrB, kb, sub); });
  __syncthreads();                      // hB(2) ready

  // P5: K(tB, l2) || softplus(accA) -> hA(3)
  INIT_ACC(accB, 2)
  mfma_phase<5, true>(B2, B3, aptrB, bq, accB,
      [&](int kb, int sub){ sp2s(accA, cptrA, kb, sub); });
  __syncthreads();                      // hA(3) ready

  // P6: K(tA, l3) || softplus(accB) -> hB(3)
  INIT_ACC(accA, 3)
  mfma_phase<6, true>(B3, B3, aptrA, bq, accA,
      [&](int kb, int sub){ sp2s(accB, cptrB, kb, sub); });
  __syncthreads();                      // hB(3) ready

  // P7: K(tB, l3) || softplus+output-dot of accA
  INIT_ACC(accB, 3)
  float pA[16], pB[16];
  #pragma unroll
  for (int i = 0; i < 16; ++i) pA[i] = 0.f;
  mfma_phase<7, false>(B3, B3, aptrB, bq, accB,
      [&](int kb, int sub){ spdot2s(accA, wv, pA, kb, sub); });

  #pragma unroll
  for (int i = 0; i < 16; ++i) pB[i] = 0.f;
  #pragma unroll
  for (int kb = 0; kb < 8; ++kb)        // tile B's dot (exposed epilogue)
    #pragma unroll
    for (int sub = 0; sub < 4; ++sub)
      spdot2s(accB, wv, pB, kb, sub);

  // cross-wave reduce: 2 regions of 64 rows x 64 partials (stride-68 pad).
  // Barrier first: other waves may still be doing P7 A-reads from hB.
  __syncthreads();
  float* redA = (float*)h_lds;
  float* redB = redA + 64 * 68;
  #pragma unroll
  for (int mi = 0; mi < 4; ++mi)
    #pragma unroll
    for (int r = 0; r < 4; ++r) {
      int row = mi * 16 + (q << 2) + r;
      redA[row * 68 + (wave << 4) + lr] = pA[mi * 4 + r];
      redB[row * 68 + (wave << 4) + lr] = pB[mi * 4 + r];
    }
  __syncthreads();

  if (tid < 128) {
    const int t = tid & 63;
    const float* red = (tid < 64) ? redA : redB;
    const float4v* rr = (const float4v*)&red[t * 68];
    float4v a = rr[0];
    #pragma unroll
    for (int i = 1; i < 16; ++i) {
      float4v b = rr[i];
      a.x += b.x; a.y += b.y; a.z += b.z; a.w += b.w;
    }
    float tot = (a.x + a.y) + (a.z + a.w);
    int row = m0 + ((tid >> 6) << 6) + t;
    if (row < 200000)
      out[row * 8 + s] = fmaf(LN2, tot, bout[s]);  // undo log2-domain
  }
#undef INIT_ACC
}

// ---------------------------------------------------------------------------
// Fallback (scratch-free), fp32 VALU — only if ws_size < 4 MiB.
// ---------------------------------------------------------------------------
__global__ __launch_bounds__(256) void series_mlp_slow(
    const float* __restrict__ coords,
    const float* __restrict__ W0, const float* __restrict__ b0,
    const float* __restrict__ Wh, const float* __restrict__ bh,
    const float* __restrict__ Wout, const float* __restrict__ bout,
    float* __restrict__ out)
{
  __shared__ float hh[64 * 256];
  __shared__ float cbuf[192];
  __shared__ float red[256];
  const int tid = threadIdx.x;
  const int s   = blockIdx.y;
  const int m0  = blockIdx.x * 64;

  if (tid < 192) cbuf[tid] = coords[m0 * 3 + tid];
  __syncthreads();
  {
    const float w0 = W0[(s * 3 + 0) * 256 + tid];
    const float w1 = W0[(s * 3 + 1) * 256 + tid];
    const float w2 = W0[(s * 3 + 2) * 256 + tid];
    const float bb = b0[s * 256 + tid];
    for (int m = 0; m < 64; ++m) {
      float z = fmaf(cbuf[m * 3 + 2], w2,
                fmaf(cbuf[m * 3 + 1], w1,
                fmaf(cbuf[m * 3 + 0], w0, bb)));
      hh[m * 256 + tid] = LN2 * softplus_hat(z * LOG2E);
    }
  }
  __syncthreads();

  for (int l = 0; l < 4; ++l) {
    const float* W = Wh + (((s << 2) + l) << 16);
    const float bb = bh[((s << 2) + l) * 256 + tid];
    float acc[64];
    #pragma unroll
    for (int m = 0; m < 64; ++m) acc[m] = bb;
    for (int kc = 0; kc < 64; ++kc) {
      float w0 = W[(kc * 4 + 0) * 256 + tid];
      float w1 = W[(kc * 4 + 1) * 256 + tid];
      float w2 = W[(kc * 4 + 2) * 256 + tid];
      float w3 = W[(kc * 4 + 3) * 256 + tid];
      #pragma unroll
      for (int m = 0; m < 64; ++m) {
        float4v hv = *(const float4v*)&hh[m * 256 + kc * 4];
        acc[m] = fmaf(hv.w, w3, fmaf(hv.z, w2,
                 fmaf(hv.y, w1, fmaf(hv.x, w0, acc[m]))));
      }
    }
    __syncthreads();
    #pragma unroll
    for (int m = 0; m < 64; ++m)
      hh[m * 256 + tid] = LN2 * softplus_hat(acc[m] * LOG2E);
    __syncthreads();
  }
  {
    const int m = tid >> 2, qq = tid & 3;
    const float* wv = Wout + (s << 8);
    float sum = 0.f;
    for (int i = 0; i < 16; ++i) {
      int kk = (qq << 6) + ((((tid & 15) + i) << 2) & 63);
      float4v hv = *(const float4v*)&hh[m * 256 + kk];
      sum += hv.x * wv[kk] + hv.y * wv[kk + 1] + hv.z * wv[kk + 2] + hv.w * wv[kk + 3];
    }
    red[tid] = sum;
    __syncthreads();
    if (tid < 64)
      out[(m0 + tid) * 8 + s] =
          red[tid * 4] + red[tid * 4 + 1] + red[tid * 4 + 2] + red[tid * 4 + 3] + bout[s];
  }
}

extern "C" void kernel_launch(void* const* d_in, const int* in_sizes, int n_in,
                              void* d_out, int out_size, void* d_ws, size_t ws_size,
                              hipStream_t stream) {
  const float* coords = (const float*)d_in[0];
  const float* W0     = (const float*)d_in[1];
  const float* b0     = (const float*)d_in[2];
  const float* Wh     = (const float*)d_in[3];
  const float* bh     = (const float*)d_in[4];
  const float* Wout   = (const float*)d_in[5];
  const float* bout   = (const float*)d_in[6];
  float* out = (float*)d_out;

  const size_t WT_BYTES = (size_t)8 * 4 * 256 * 256 * 2;   // 4 MiB bf16 slabs
  if (ws_size >= WT_BYTES) {
    unsigned short* Wt = (unsigned short*)d_ws;
    convert_wh<<<8192, 256, 0, stream>>>(Wh, Wt);
    // 1563 m-blocks x 128 rows x 8 series; 1562*128+64 = 200000 (tail tile1 dead)
    series_mlp<<<dim3(12504), dim3(256), 0, stream>>>(
        coords, W0, b0, bh, Wout, bout, Wt, out);
  } else {
    series_mlp_slow<<<dim3(3125, 8), dim3(256), 0, stream>>>(
        coords, W0, b0, Wh, bh, Wout, bout, out);
  }
  // second tuple output: echo coords
  hipMemcpyAsync(out + (size_t)200000 * 8, coords,
                 (size_t)200000 * 3 * sizeof(float),
                 hipMemcpyDeviceToDevice, stream);
}